// Round 2
// baseline (634.686 us; speedup 1.0000x reference)
//
#include <hip/hip_runtime.h>

// Problem constants (TBStars2 MoE sparse block) — fp32 I/O, bf16 MFMA compute
#define T 4096
#define Hdim 1024
#define Fdim 2048
#define NE 8
#define TOPK 2
#define TK (T*TOPK)

// GEMM tiling
#define BM 64
#define BN 64
#define BK 32
#define LDSP 40   // padded LDS row stride (elems): 80B, 16B-aligned chunks, <=2-way bank alias

typedef unsigned short ushort_t;
typedef __attribute__((ext_vector_type(8))) short bf16x8;   // 8 x bf16 (4 VGPRs)
typedef __attribute__((ext_vector_type(4))) float floatx4;  // mfma accumulator

__device__ __forceinline__ ushort_t f2bf(float f) {
    unsigned u = __float_as_uint(f);
    u += 0x7fff + ((u >> 16) & 1);   // round-to-nearest-even
    return (ushort_t)(u >> 16);
}

// pack 8 fp32 (two float4) -> 8 bf16 as uint4 (16 B)
__device__ __forceinline__ uint4 cvt8(const float4 a, const float4 b) {
    uint4 r;
    r.x = (unsigned)f2bf(a.x) | ((unsigned)f2bf(a.y) << 16);
    r.y = (unsigned)f2bf(a.z) | ((unsigned)f2bf(a.w) << 16);
    r.z = (unsigned)f2bf(b.x) | ((unsigned)f2bf(b.y) << 16);
    r.w = (unsigned)f2bf(b.z) | ((unsigned)f2bf(b.w) << 16);
    return r;
}

// ---------------------------------------------------------------------------
// K0: zero per-expert counts
__global__ void zero_counts_kernel(int* counts) {
    if (threadIdx.x < NE) counts[threadIdx.x] = 0;
}

// ---------------------------------------------------------------------------
// K1: router. One wave per token. fp32 throughout.
__global__ __launch_bounds__(64) void router_kernel(
    const float* __restrict__ hs, const float* __restrict__ gw,
    float* __restrict__ logits_out,
    int* __restrict__ counts, int* __restrict__ tok_slot, float* __restrict__ tok_wt)
{
    const int t = blockIdx.x;
    const int lane = threadIdx.x;

    float hreg[16];
#pragma unroll
    for (int i = 0; i < 16; ++i)
        hreg[i] = hs[(long)t * Hdim + lane + 64 * i];

    float acc[NE];
#pragma unroll
    for (int e = 0; e < NE; ++e) {
        float s = 0.f;
#pragma unroll
        for (int i = 0; i < 16; ++i)
            s += hreg[i] * gw[e * Hdim + lane + 64 * i];
#pragma unroll
        for (int off = 32; off > 0; off >>= 1)
            s += __shfl_xor(s, off, 64);
        acc[e] = s;
    }

    if (lane < NE)
        logits_out[t * NE + lane] = acc[lane];

    if (lane == 0) {
        // top-2, first-occurrence tie-break (matches lax.top_k)
        int i1 = 0;
#pragma unroll
        for (int e = 1; e < NE; ++e) if (acc[e] > acc[i1]) i1 = e;
        int i2 = -1;
#pragma unroll
        for (int e = 0; e < NE; ++e) {
            if (e == i1) continue;
            if (i2 < 0 || acc[e] > acc[i2]) i2 = e;
        }
        // renormalized top-2 weights (softmax denominator cancels)
        float m  = acc[i1];
        float p2 = __expf(acc[i2] - m);
        float z  = 1.f + p2;
        int pos1 = atomicAdd(&counts[i1], 1);
        tok_slot[i1 * T + pos1] = t * TOPK + 0;
        tok_wt [i1 * T + pos1] = 1.f / z;
        int pos2 = atomicAdd(&counts[i2], 1);
        tok_slot[i2 * T + pos2] = t * TOPK + 1;
        tok_wt [i2 * T + pos2] = p2 / z;
    }
}

// ---------------------------------------------------------------------------
// K2: gather-GEMM1 + SwiGLU.  act[slot, f] = silu(x@Wg^T) * (x@Wu^T)  (bf16 out)
// fp32 inputs, cvt->bf16 at LDS staging. grid: (F/BN, T/BM, NE), 4 waves.
__global__ __launch_bounds__(256) void gemm1_kernel(
    const float* __restrict__ hs, const float* __restrict__ w1,
    const int* __restrict__ counts, const int* __restrict__ tok_slot,
    ushort_t* __restrict__ actb)
{
    const int e = blockIdx.z;
    const int cnt = counts[e];
    const int row0 = blockIdx.y * BM;
    if (row0 >= cnt) return;
    const int f0 = blockIdx.x * BN;

    __shared__ short Xs[BM * LDSP];
    __shared__ short Gs[BN * LDSP];
    __shared__ short Us[BN * LDSP];
    __shared__ int slotLds[BM];

    const int tid = threadIdx.x;
    if (tid < BM) {
        int idx = row0 + tid;
        slotLds[tid] = (idx < cnt) ? tok_slot[e * T + idx] : -1;
    }
    __syncthreads();

    // staging: each thread covers (row = tid>>2, 8-elem segment = (tid&3)*8)
    const int srow = tid >> 2;
    const int sseg = (tid & 3) * 8;
    const int slot_s = slotLds[srow];
    const float* xsrc = (slot_s >= 0)
        ? hs + (long)(slot_s >> 1) * Hdim + sseg : nullptr;
    const float* gsrc = w1 + ((long)(e * 2 * Fdim) + (f0 + srow)) * Hdim + sseg;
    const float* usrc = gsrc + (long)Fdim * Hdim;

    const int lane = tid & 63;
    const int w = tid >> 6;
    const int wm = (w >> 1) * 32, wn = (w & 1) * 32;
    const int fr = lane & 15, fg = lane >> 4;

    floatx4 accg[2][2] = {};
    floatx4 accu[2][2] = {};

    for (int k0 = 0; k0 < Hdim; k0 += BK) {
        float4 xv0 = make_float4(0.f,0.f,0.f,0.f), xv1 = xv0;
        if (slot_s >= 0) {
            xv0 = *(const float4*)(xsrc + k0);
            xv1 = *(const float4*)(xsrc + k0 + 4);
        }
        float4 gv0 = *(const float4*)(gsrc + k0);
        float4 gv1 = *(const float4*)(gsrc + k0 + 4);
        float4 uv0 = *(const float4*)(usrc + k0);
        float4 uv1 = *(const float4*)(usrc + k0 + 4);

        __syncthreads();   // prev iter's frag reads done
        *(uint4*)&Xs[srow * LDSP + sseg] = cvt8(xv0, xv1);
        *(uint4*)&Gs[srow * LDSP + sseg] = cvt8(gv0, gv1);
        *(uint4*)&Us[srow * LDSP + sseg] = cvt8(uv0, uv1);
        __syncthreads();

        bf16x8 a0 = *(bf16x8*)&Xs[(wm +      fr) * LDSP + fg * 8];
        bf16x8 a1 = *(bf16x8*)&Xs[(wm + 16 + fr) * LDSP + fg * 8];
        bf16x8 g0 = *(bf16x8*)&Gs[(wn +      fr) * LDSP + fg * 8];
        bf16x8 g1 = *(bf16x8*)&Gs[(wn + 16 + fr) * LDSP + fg * 8];
        bf16x8 u0 = *(bf16x8*)&Us[(wn +      fr) * LDSP + fg * 8];
        bf16x8 u1 = *(bf16x8*)&Us[(wn + 16 + fr) * LDSP + fg * 8];

        accg[0][0] = __builtin_amdgcn_mfma_f32_16x16x32_bf16(a0, g0, accg[0][0], 0, 0, 0);
        accg[0][1] = __builtin_amdgcn_mfma_f32_16x16x32_bf16(a0, g1, accg[0][1], 0, 0, 0);
        accg[1][0] = __builtin_amdgcn_mfma_f32_16x16x32_bf16(a1, g0, accg[1][0], 0, 0, 0);
        accg[1][1] = __builtin_amdgcn_mfma_f32_16x16x32_bf16(a1, g1, accg[1][1], 0, 0, 0);
        accu[0][0] = __builtin_amdgcn_mfma_f32_16x16x32_bf16(a0, u0, accu[0][0], 0, 0, 0);
        accu[0][1] = __builtin_amdgcn_mfma_f32_16x16x32_bf16(a0, u1, accu[0][1], 0, 0, 0);
        accu[1][0] = __builtin_amdgcn_mfma_f32_16x16x32_bf16(a1, u0, accu[1][0], 0, 0, 0);
        accu[1][1] = __builtin_amdgcn_mfma_f32_16x16x32_bf16(a1, u1, accu[1][1], 0, 0, 0);
    }

    // epilogue: SwiGLU, bf16 act rows
#pragma unroll
    for (int ms = 0; ms < 2; ++ms) {
#pragma unroll
        for (int ns = 0; ns < 2; ++ns) {
#pragma unroll
            for (int j = 0; j < 4; ++j) {
                int m = wm + ms * 16 + fg * 4 + j;
                int slot = slotLds[m];
                if (slot >= 0) {
                    int fcol = f0 + wn + ns * 16 + fr;
                    float g = accg[ms][ns][j];
                    float u = accu[ms][ns][j];
                    float a = (g / (1.f + __expf(-g))) * u;   // silu(g)*u
                    actb[(long)slot * Fdim + fcol] = f2bf(a);
                }
            }
        }
    }
}

// ---------------------------------------------------------------------------
// K3: gather-GEMM2.  partial[slot, h] = wt * (act[slot,:] @ w2[e,h,:])  (fp32)
// A: bf16 act (direct stage). B: fp32 w2 (cvt at stage). grid: (H/BN, T/BM, NE)
__global__ __launch_bounds__(256) void gemm2_kernel(
    const ushort_t* __restrict__ actb, const float* __restrict__ w2,
    const int* __restrict__ counts, const int* __restrict__ tok_slot,
    const float* __restrict__ tok_wt, float* __restrict__ partial)
{
    const int e = blockIdx.z;
    const int cnt = counts[e];
    const int row0 = blockIdx.y * BM;
    if (row0 >= cnt) return;
    const int h0 = blockIdx.x * BN;

    __shared__ short As[BM * LDSP];
    __shared__ short Ws[BN * LDSP];
    __shared__ int   slotLds[BM];
    __shared__ float wtLds[BM];

    const int tid = threadIdx.x;
    if (tid < BM) {
        int idx = row0 + tid;
        bool ok = idx < cnt;
        slotLds[tid] = ok ? tok_slot[e * T + idx] : -1;
        wtLds[tid]   = ok ? tok_wt [e * T + idx] : 0.f;
    }
    __syncthreads();

    const int srow = tid >> 2;
    const int sseg = (tid & 3) * 8;
    const int slot_s = slotLds[srow];
    const ushort_t* asrc = (slot_s >= 0)
        ? actb + (long)slot_s * Fdim + sseg : nullptr;
    const float* wsrc = w2 + ((long)(e * Hdim) + (h0 + srow)) * Fdim + sseg;

    const int lane = tid & 63;
    const int w = tid >> 6;
    const int wm = (w >> 1) * 32, wn = (w & 1) * 32;
    const int fr = lane & 15, fg = lane >> 4;

    floatx4 acc[2][2] = {};

    for (int k0 = 0; k0 < Fdim; k0 += BK) {
        uint4 av = make_uint4(0u,0u,0u,0u);
        if (slot_s >= 0) av = *(const uint4*)(asrc + k0);
        float4 wv0 = *(const float4*)(wsrc + k0);
        float4 wv1 = *(const float4*)(wsrc + k0 + 4);

        __syncthreads();
        *(uint4*)&As[srow * LDSP + sseg] = av;
        *(uint4*)&Ws[srow * LDSP + sseg] = cvt8(wv0, wv1);
        __syncthreads();

        bf16x8 a0 = *(bf16x8*)&As[(wm +      fr) * LDSP + fg * 8];
        bf16x8 a1 = *(bf16x8*)&As[(wm + 16 + fr) * LDSP + fg * 8];
        bf16x8 b0 = *(bf16x8*)&Ws[(wn +      fr) * LDSP + fg * 8];
        bf16x8 b1 = *(bf16x8*)&Ws[(wn + 16 + fr) * LDSP + fg * 8];

        acc[0][0] = __builtin_amdgcn_mfma_f32_16x16x32_bf16(a0, b0, acc[0][0], 0, 0, 0);
        acc[0][1] = __builtin_amdgcn_mfma_f32_16x16x32_bf16(a0, b1, acc[0][1], 0, 0, 0);
        acc[1][0] = __builtin_amdgcn_mfma_f32_16x16x32_bf16(a1, b0, acc[1][0], 0, 0, 0);
        acc[1][1] = __builtin_amdgcn_mfma_f32_16x16x32_bf16(a1, b1, acc[1][1], 0, 0, 0);
    }

#pragma unroll
    for (int ms = 0; ms < 2; ++ms) {
#pragma unroll
        for (int ns = 0; ns < 2; ++ns) {
#pragma unroll
            for (int j = 0; j < 4; ++j) {
                int m = wm + ms * 16 + fg * 4 + j;
                int slot = slotLds[m];
                if (slot >= 0) {
                    int hcol = h0 + wn + ns * 16 + fr;
                    partial[(long)slot * Hdim + hcol] = acc[ms][ns][j] * wtLds[m];
                }
            }
        }
    }
}

// ---------------------------------------------------------------------------
// K4: combine the two (token,k) partials -> fp32 final hidden states
__global__ __launch_bounds__(256) void combine_kernel(
    const float* __restrict__ partial, float* __restrict__ out)
{
    long i = (long)blockIdx.x * 256 + threadIdx.x;   // over T*H/4 float4 groups
    int t  = (int)(i / (Hdim / 4));
    int h4 = (int)(i % (Hdim / 4));
    const float4 p0 = *(const float4*)&partial[(long)(2 * t    ) * Hdim + h4 * 4];
    const float4 p1 = *(const float4*)&partial[(long)(2 * t + 1) * Hdim + h4 * 4];
    float4 s;
    s.x = p0.x + p1.x; s.y = p0.y + p1.y; s.z = p0.z + p1.z; s.w = p0.w + p1.w;
    *(float4*)&out[(long)t * Hdim + h4 * 4] = s;
}

// ---------------------------------------------------------------------------
extern "C" void kernel_launch(void* const* d_in, const int* in_sizes, int n_in,
                              void* d_out, int out_size, void* d_ws, size_t ws_size,
                              hipStream_t stream)
{
    const float* hs = (const float*)d_in[0];   // [T, H] fp32
    const float* gw = (const float*)d_in[1];   // [E, H] fp32
    const float* w1 = (const float*)d_in[2];   // [E, 2F, H] fp32
    const float* w2 = (const float*)d_in[3];   // [E, H, F] fp32
    // d_in[4] = top_k (always 2)

    float* out        = (float*)d_out;          // [T*H] final hidden (fp32)
    float* logits_out = out + (long)T * Hdim;   // [T*E] router logits (fp32)

    // workspace layout
    char* ws = (char*)d_ws;
    size_t off = 0;
    int* counts = (int*)(ws + off);            off += 256;
    int* tok_slot = (int*)(ws + off);          off += (size_t)NE * T * sizeof(int);    // 128 KB
    float* tok_wt = (float*)(ws + off);        off += (size_t)NE * T * sizeof(float);  // 128 KB
    off = (off + 255) & ~(size_t)255;
    ushort_t* actb = (ushort_t*)(ws + off);    off += (size_t)TK * Fdim * sizeof(ushort_t); // 32 MB
    off = (off + 255) & ~(size_t)255;
    float* partial = (float*)(ws + off);       off += (size_t)TK * Hdim * sizeof(float);    // 32 MB

    zero_counts_kernel<<<1, 64, 0, stream>>>(counts);
    router_kernel<<<T, 64, 0, stream>>>(hs, gw, logits_out, counts, tok_slot, tok_wt);
    gemm1_kernel<<<dim3(Fdim / BN, T / BM, NE), 256, 0, stream>>>(hs, w1, counts, tok_slot, actb);
    gemm2_kernel<<<dim3(Hdim / BN, T / BM, NE), 256, 0, stream>>>(actb, w2, counts, tok_slot, tok_wt, partial);
    combine_kernel<<<(int)((long)T * Hdim / 4 / 256), 256, 0, stream>>>(partial, out);
}

// Round 3
// 531.520 us; speedup vs baseline: 1.1941x; 1.1941x over previous
//
#include <hip/hip_runtime.h>

// TBStars2 MoE sparse block — fp32 I/O, bf16 MFMA compute (m97-style GEMMs)
#define T 4096
#define Hdim 1024
#define Fdim 2048
#define NE 8
#define TOPK 2
#define TK (T*TOPK)

typedef unsigned short ushort_t;
typedef __attribute__((ext_vector_type(8))) short bf16x8;   // 8 x bf16 (4 VGPRs)
typedef __attribute__((ext_vector_type(4))) float floatx4;  // mfma accumulator

__device__ __forceinline__ ushort_t f2bf(float f) {
    unsigned u = __float_as_uint(f);
    u += 0x7fff + ((u >> 16) & 1);   // RNE
    return (ushort_t)(u >> 16);
}
__device__ __forceinline__ uint4 cvt8(const float4 a, const float4 b) {
    uint4 r;
    r.x = (unsigned)f2bf(a.x) | ((unsigned)f2bf(a.y) << 16);
    r.y = (unsigned)f2bf(a.z) | ((unsigned)f2bf(a.w) << 16);
    r.z = (unsigned)f2bf(b.x) | ((unsigned)f2bf(b.y) << 16);
    r.w = (unsigned)f2bf(b.z) | ((unsigned)f2bf(b.w) << 16);
    return r;
}
// async 16B global->LDS (per-lane gather src OK; LDS dest = wave base + lane*16)
__device__ __forceinline__ void gld16(const ushort_t* g, short* l) {
    __builtin_amdgcn_global_load_lds((const __attribute__((address_space(1))) void*)g,
                                     (__attribute__((address_space(3))) void*)l, 16, 0, 0);
}

// ---------------------------------------------------------------------------
// K0: zero out[0..T*H) (gemm2 atomic-accumulates into it) + counts
__global__ __launch_bounds__(256) void init_kernel(float* __restrict__ out, int* __restrict__ counts) {
    long i = (long)blockIdx.x * 256 + threadIdx.x;      // T*H/4 groups
    float4 z = make_float4(0.f, 0.f, 0.f, 0.f);
    *(float4*)&out[i * 4] = z;
    if (blockIdx.x == 0 && threadIdx.x < NE) counts[threadIdx.x] = 0;
}

// K0b: fp32 -> bf16 bulk convert (grid-stride, 8 elems/thread/iter)
__global__ __launch_bounds__(256) void cvt_kernel(const float* __restrict__ src,
                                                  ushort_t* __restrict__ dst, long n8) {
    long stride = (long)gridDim.x * 256;
    for (long i = (long)blockIdx.x * 256 + threadIdx.x; i < n8; i += stride) {
        float4 a = *(const float4*)(src + i * 8);
        float4 b = *(const float4*)(src + i * 8 + 4);
        *(uint4*)(dst + i * 8) = cvt8(a, b);
    }
}

// ---------------------------------------------------------------------------
// K1: router. One wave per token, fp32.
__global__ __launch_bounds__(64) void router_kernel(
    const float* __restrict__ hs, const float* __restrict__ gw,
    float* __restrict__ logits_out,
    int* __restrict__ counts, int* __restrict__ tok_slot, float* __restrict__ tok_wt)
{
    const int t = blockIdx.x;
    const int lane = threadIdx.x;

    float hreg[16];
#pragma unroll
    for (int i = 0; i < 16; ++i)
        hreg[i] = hs[(long)t * Hdim + lane + 64 * i];

    float acc[NE];
#pragma unroll
    for (int e = 0; e < NE; ++e) {
        float s = 0.f;
#pragma unroll
        for (int i = 0; i < 16; ++i)
            s += hreg[i] * gw[e * Hdim + lane + 64 * i];
#pragma unroll
        for (int off = 32; off > 0; off >>= 1)
            s += __shfl_xor(s, off, 64);
        acc[e] = s;
    }

    if (lane < NE) logits_out[t * NE + lane] = acc[lane];

    if (lane == 0) {
        int i1 = 0;
#pragma unroll
        for (int e = 1; e < NE; ++e) if (acc[e] > acc[i1]) i1 = e;
        int i2 = -1;
#pragma unroll
        for (int e = 0; e < NE; ++e) {
            if (e == i1) continue;
            if (i2 < 0 || acc[e] > acc[i2]) i2 = e;
        }
        float p2 = __expf(acc[i2] - acc[i1]);
        float z  = 1.f + p2;
        int pos1 = atomicAdd(&counts[i1], 1);
        tok_slot[i1 * T + pos1] = t * TOPK + 0;
        tok_wt [i1 * T + pos1] = 1.f / z;
        int pos2 = atomicAdd(&counts[i2], 1);
        tok_slot[i2 * T + pos2] = t * TOPK + 1;
        tok_wt [i2 * T + pos2] = p2 / z;
    }
}

// ---------------------------------------------------------------------------
// K2: gather-GEMM1 + SwiGLU. Tile: 128 rows x 64 f-cols (gate+up both staged).
// A: gathered hs_bf rows; B: w1bf rows [f0..f0+64) gate + [F+f0..) up.
// Staging via global_load_lds x16B. 4 waves, each 64 rows x (32 gate + 32 up).
__global__ __launch_bounds__(256) void gemm1_kernel(
    const ushort_t* __restrict__ hsb, const ushort_t* __restrict__ w1b,
    const int* __restrict__ counts, const int* __restrict__ tok_slot,
    ushort_t* __restrict__ actb)
{
    const int e = blockIdx.z;
    const int cnt = counts[e];
    const int row0 = blockIdx.y * 128;
    if (row0 >= cnt) return;
    const int f0 = blockIdx.x * 64;

    __shared__ short As[128 * 32];    // 8 KB, row stride 32 elems (64 B)
    __shared__ short Bs[128 * 32];    // rows 0-63 gate, 64-127 up
    __shared__ int slotLds[128];

    const int tid = threadIdx.x;
    if (tid < 128) {
        int idx = row0 + tid;
        slotLds[tid] = (idx < cnt) ? tok_slot[e * T + idx] : -1;
    }
    __syncthreads();

    // staging chunks: c0 = tid (rows 0-63), c1 = 256+tid (rows 64-127); 4 chunks/row
    const int rA0 = tid >> 2,      rA1 = 64 + (tid >> 2);
    const int seg = (tid & 3) * 8;
    int s0 = slotLds[rA0], s1 = slotLds[rA1];
    const ushort_t* srcA0 = hsb + (long)((s0 >= 0 ? (s0 >> 1) : 0)) * Hdim + seg;
    const ushort_t* srcA1 = hsb + (long)((s1 >= 0 ? (s1 >> 1) : 0)) * Hdim + seg;
    const ushort_t* srcB0 = w1b + ((long)e * 2 * Fdim + (f0 + rA0)) * Hdim + seg;          // gate
    const ushort_t* srcB1 = w1b + ((long)e * 2 * Fdim + Fdim + (f0 + rA0)) * Hdim + seg;   // up

    const int lane = tid & 63;
    const int w = tid >> 6;
    const int wm = (w >> 1) * 64;     // 64 output rows per wave
    const int wn = (w & 1) * 32;      // 32 f-cols per wave (both gate & up)
    const int fr = lane & 15, fg = lane >> 4;

    floatx4 accg[4][2] = {};
    floatx4 accu[4][2] = {};

    for (int k0 = 0; k0 < Hdim; k0 += 32) {
        __syncthreads();                         // LDS free (and slotLds visible, iter 0)
        gld16(srcA0 + k0, &As[tid * 8]);
        gld16(srcA1 + k0, &As[(256 + tid) * 8]);
        gld16(srcB0 + k0, &Bs[tid * 8]);
        gld16(srcB1 + k0, &Bs[(256 + tid) * 8]);
        __syncthreads();                         // drains vmcnt -> tiles visible

        bf16x8 a[4], g[2], u[2];
#pragma unroll
        for (int ms = 0; ms < 4; ++ms)
            a[ms] = *(bf16x8*)&As[(wm + ms * 16 + fr) * 32 + fg * 8];
#pragma unroll
        for (int ns = 0; ns < 2; ++ns) {
            g[ns] = *(bf16x8*)&Bs[(wn + ns * 16 + fr) * 32 + fg * 8];
            u[ns] = *(bf16x8*)&Bs[(64 + wn + ns * 16 + fr) * 32 + fg * 8];
        }
#pragma unroll
        for (int ms = 0; ms < 4; ++ms)
#pragma unroll
            for (int ns = 0; ns < 2; ++ns) {
                accg[ms][ns] = __builtin_amdgcn_mfma_f32_16x16x32_bf16(a[ms], g[ns], accg[ms][ns], 0, 0, 0);
                accu[ms][ns] = __builtin_amdgcn_mfma_f32_16x16x32_bf16(a[ms], u[ns], accu[ms][ns], 0, 0, 0);
            }
    }

    // epilogue: SwiGLU -> bf16 act rows
#pragma unroll
    for (int ms = 0; ms < 4; ++ms)
#pragma unroll
        for (int ns = 0; ns < 2; ++ns)
#pragma unroll
            for (int j = 0; j < 4; ++j) {
                int m = wm + ms * 16 + fg * 4 + j;
                int slot = slotLds[m];
                if (slot >= 0) {
                    int fcol = f0 + wn + ns * 16 + fr;
                    float gv = accg[ms][ns][j];
                    float uv = accu[ms][ns][j];
                    float av = (gv / (1.f + __expf(-gv))) * uv;
                    actb[(long)slot * Fdim + fcol] = f2bf(av);
                }
            }
}

// ---------------------------------------------------------------------------
// K3: gather-GEMM2, m97-style 128x128, K=F. out[t,h] += wt * act@w2^T (atomic).
__global__ __launch_bounds__(256) void gemm2_kernel(
    const ushort_t* __restrict__ actb, const ushort_t* __restrict__ w2b,
    const int* __restrict__ counts, const int* __restrict__ tok_slot,
    const float* __restrict__ tok_wt, float* __restrict__ out)
{
    const int e = blockIdx.z;
    const int cnt = counts[e];
    const int row0 = blockIdx.y * 128;
    if (row0 >= cnt) return;
    const int h0 = blockIdx.x * 128;

    __shared__ short As[128 * 32];
    __shared__ short Bs[128 * 32];
    __shared__ int   slotLds[128];
    __shared__ float wtLds[128];

    const int tid = threadIdx.x;
    if (tid < 128) {
        int idx = row0 + tid;
        bool ok = idx < cnt;
        slotLds[tid] = ok ? tok_slot[e * T + idx] : -1;
        wtLds[tid]   = ok ? tok_wt [e * T + idx] : 0.f;
    }
    __syncthreads();

    const int rA0 = tid >> 2, rA1 = 64 + (tid >> 2);
    const int seg = (tid & 3) * 8;
    int s0 = slotLds[rA0], s1 = slotLds[rA1];
    const ushort_t* srcA0 = actb + (long)(s0 >= 0 ? s0 : 0) * Fdim + seg;
    const ushort_t* srcA1 = actb + (long)(s1 >= 0 ? s1 : 0) * Fdim + seg;
    const ushort_t* srcB0 = w2b + ((long)e * Hdim + (h0 + rA0)) * Fdim + seg;
    const ushort_t* srcB1 = w2b + ((long)e * Hdim + (h0 + rA1)) * Fdim + seg;

    const int lane = tid & 63;
    const int w = tid >> 6;
    const int wm = (w >> 1) * 64;
    const int wn = (w & 1) * 64;
    const int fr = lane & 15, fg = lane >> 4;

    floatx4 acc[4][4] = {};

    for (int k0 = 0; k0 < Fdim; k0 += 32) {
        __syncthreads();
        gld16(srcA0 + k0, &As[tid * 8]);
        gld16(srcA1 + k0, &As[(256 + tid) * 8]);
        gld16(srcB0 + k0, &Bs[tid * 8]);
        gld16(srcB1 + k0, &Bs[(256 + tid) * 8]);
        __syncthreads();

        bf16x8 a[4], b[4];
#pragma unroll
        for (int ms = 0; ms < 4; ++ms)
            a[ms] = *(bf16x8*)&As[(wm + ms * 16 + fr) * 32 + fg * 8];
#pragma unroll
        for (int ns = 0; ns < 4; ++ns)
            b[ns] = *(bf16x8*)&Bs[(wn + ns * 16 + fr) * 32 + fg * 8];
#pragma unroll
        for (int ms = 0; ms < 4; ++ms)
#pragma unroll
            for (int ns = 0; ns < 4; ++ns)
                acc[ms][ns] = __builtin_amdgcn_mfma_f32_16x16x32_bf16(a[ms], b[ns], acc[ms][ns], 0, 0, 0);
    }

#pragma unroll
    for (int ms = 0; ms < 4; ++ms)
#pragma unroll
        for (int ns = 0; ns < 4; ++ns)
#pragma unroll
            for (int j = 0; j < 4; ++j) {
                int m = wm + ms * 16 + fg * 4 + j;
                int slot = slotLds[m];
                if (slot >= 0) {
                    int t = slot >> 1;
                    int hcol = h0 + wn + ns * 16 + fr;
                    atomicAdd(&out[(long)t * Hdim + hcol], acc[ms][ns][j] * wtLds[m]);
                }
            }
}

// ---------------------------------------------------------------------------
extern "C" void kernel_launch(void* const* d_in, const int* in_sizes, int n_in,
                              void* d_out, int out_size, void* d_ws, size_t ws_size,
                              hipStream_t stream)
{
    const float* hs = (const float*)d_in[0];   // [T, H] fp32
    const float* gw = (const float*)d_in[1];   // [E, H] fp32
    const float* w1 = (const float*)d_in[2];   // [E, 2F, H] fp32
    const float* w2 = (const float*)d_in[3];   // [E, H, F] fp32

    float* out        = (float*)d_out;          // [T*H] final hidden (fp32)
    float* logits_out = out + (long)T * Hdim;   // [T*E] router logits (fp32)

    // workspace layout (~104.3 MB):
    char* ws = (char*)d_ws;
    size_t off = 0;
    int* counts = (int*)(ws + off);          off += 256;
    int* tok_slot = (int*)(ws + off);        off += (size_t)NE * T * sizeof(int);
    float* tok_wt = (float*)(ws + off);      off += (size_t)NE * T * sizeof(float);
    off = (off + 255) & ~(size_t)255;
    ushort_t* hsb = (ushort_t*)(ws + off);   off += (size_t)T * Hdim * sizeof(ushort_t);   // 8 MB
    off = (off + 255) & ~(size_t)255;
    ushort_t* w1b = (ushort_t*)(ws + off);   off += (size_t)NE * 2 * Fdim * Hdim * sizeof(ushort_t); // 64 MB
    ushort_t* w2b = w1b;   // reused AFTER gemm1 completes (stream-ordered) — 32 MB
    off = (off + 255) & ~(size_t)255;
    ushort_t* actb = (ushort_t*)(ws + off);  off += (size_t)TK * Fdim * sizeof(ushort_t);  // 32 MB

    init_kernel<<<(int)((long)T * Hdim / 4 / 256), 256, 0, stream>>>(out, counts);
    cvt_kernel<<<1024, 256, 0, stream>>>(hs, hsb, (long)T * Hdim / 8);
    cvt_kernel<<<2048, 256, 0, stream>>>(w1, w1b, (long)NE * 2 * Fdim * Hdim / 8);
    router_kernel<<<T, 64, 0, stream>>>(hs, gw, logits_out, counts, tok_slot, tok_wt);
    gemm1_kernel<<<dim3(Fdim / 64, T / 128, NE), 256, 0, stream>>>(hsb, w1b, counts, tok_slot, actb);
    cvt_kernel<<<2048, 256, 0, stream>>>(w2, w2b, (long)NE * Hdim * Fdim / 8);   // overwrites w1b: safe, stream-ordered
    gemm2_kernel<<<dim3(Hdim / 128, T / 128, NE), 256, 0, stream>>>(actb, w2b, counts, tok_slot, tok_wt, out);
}

// Round 4
// 527.895 us; speedup vs baseline: 1.2023x; 1.0069x over previous
//
#include <hip/hip_runtime.h>

// TBStars2 MoE sparse block — fp32 I/O, bf16 MFMA compute (m97-style GEMMs)
#define T 4096
#define Hdim 1024
#define Fdim 2048
#define NE 8
#define TOPK 2
#define TK (T*TOPK)

typedef unsigned short ushort_t;
typedef __attribute__((ext_vector_type(8))) short bf16x8;   // 8 x bf16 (4 VGPRs)
typedef __attribute__((ext_vector_type(4))) float floatx4;  // mfma accumulator

__device__ __forceinline__ ushort_t f2bf(float f) {
    unsigned u = __float_as_uint(f);
    u += 0x7fff + ((u >> 16) & 1);   // RNE
    return (ushort_t)(u >> 16);
}
__device__ __forceinline__ uint4 cvt8(const float4 a, const float4 b) {
    uint4 r;
    r.x = (unsigned)f2bf(a.x) | ((unsigned)f2bf(a.y) << 16);
    r.y = (unsigned)f2bf(a.z) | ((unsigned)f2bf(a.w) << 16);
    r.z = (unsigned)f2bf(b.x) | ((unsigned)f2bf(b.y) << 16);
    r.w = (unsigned)f2bf(b.z) | ((unsigned)f2bf(b.w) << 16);
    return r;
}
// async 16B global->LDS (per-lane gather src; LDS dest = wave base + lane*16)
__device__ __forceinline__ void gld16(const ushort_t* g, short* l) {
    __builtin_amdgcn_global_load_lds((const __attribute__((address_space(1))) void*)g,
                                     (__attribute__((address_space(3))) void*)l, 16, 0, 0);
}

// ---------------------------------------------------------------------------
// K0: zero per-expert counts only (gemm2 no longer atomically accumulates)
__global__ void init_kernel(int* __restrict__ counts) {
    if (threadIdx.x < NE) counts[threadIdx.x] = 0;
}

// K0b: fp32 -> bf16 bulk convert (grid-stride, 8 elems/thread/iter)
__global__ __launch_bounds__(256) void cvt_kernel(const float* __restrict__ src,
                                                  ushort_t* __restrict__ dst, long n8) {
    long stride = (long)gridDim.x * 256;
    for (long i = (long)blockIdx.x * 256 + threadIdx.x; i < n8; i += stride) {
        float4 a = *(const float4*)(src + i * 8);
        float4 b = *(const float4*)(src + i * 8 + 4);
        *(uint4*)(dst + i * 8) = cvt8(a, b);
    }
}

// ---------------------------------------------------------------------------
// K1: router. One wave per token, fp32.
__global__ __launch_bounds__(64) void router_kernel(
    const float* __restrict__ hs, const float* __restrict__ gw,
    float* __restrict__ logits_out,
    int* __restrict__ counts, int* __restrict__ tok_slot, float* __restrict__ tok_wt)
{
    const int t = blockIdx.x;
    const int lane = threadIdx.x;

    float hreg[16];
#pragma unroll
    for (int i = 0; i < 16; ++i)
        hreg[i] = hs[(long)t * Hdim + lane + 64 * i];

    float acc[NE];
#pragma unroll
    for (int e = 0; e < NE; ++e) {
        float s = 0.f;
#pragma unroll
        for (int i = 0; i < 16; ++i)
            s += hreg[i] * gw[e * Hdim + lane + 64 * i];
#pragma unroll
        for (int off = 32; off > 0; off >>= 1)
            s += __shfl_xor(s, off, 64);
        acc[e] = s;
    }

    if (lane < NE) logits_out[t * NE + lane] = acc[lane];

    if (lane == 0) {
        int i1 = 0;
#pragma unroll
        for (int e = 1; e < NE; ++e) if (acc[e] > acc[i1]) i1 = e;
        int i2 = -1;
#pragma unroll
        for (int e = 0; e < NE; ++e) {
            if (e == i1) continue;
            if (i2 < 0 || acc[e] > acc[i2]) i2 = e;
        }
        float p2 = __expf(acc[i2] - acc[i1]);
        float z  = 1.f + p2;
        int pos1 = atomicAdd(&counts[i1], 1);
        tok_slot[i1 * T + pos1] = t * TOPK + 0;
        tok_wt [i1 * T + pos1] = 1.f / z;
        int pos2 = atomicAdd(&counts[i2], 1);
        tok_slot[i2 * T + pos2] = t * TOPK + 1;
        tok_wt [i2 * T + pos2] = p2 / z;
    }
}

// ---------------------------------------------------------------------------
// K2: gather-GEMM1 + SwiGLU. Tile: 128 rows x 64 f-cols (gate+up both staged).
__global__ __launch_bounds__(256) void gemm1_kernel(
    const ushort_t* __restrict__ hsb, const ushort_t* __restrict__ w1b,
    const int* __restrict__ counts, const int* __restrict__ tok_slot,
    ushort_t* __restrict__ actb)
{
    const int e = blockIdx.z;
    const int cnt = counts[e];
    const int row0 = blockIdx.y * 128;
    if (row0 >= cnt) return;
    const int f0 = blockIdx.x * 64;

    __shared__ short As[128 * 32];    // 8 KB, row stride 32 elems (64 B)
    __shared__ short Bs[128 * 32];    // rows 0-63 gate, 64-127 up
    __shared__ int slotLds[128];

    const int tid = threadIdx.x;
    if (tid < 128) {
        int idx = row0 + tid;
        slotLds[tid] = (idx < cnt) ? tok_slot[e * T + idx] : -1;
    }
    __syncthreads();

    const int rA0 = tid >> 2,      rA1 = 64 + (tid >> 2);
    const int seg = (tid & 3) * 8;
    int s0 = slotLds[rA0], s1 = slotLds[rA1];
    const ushort_t* srcA0 = hsb + (long)((s0 >= 0 ? (s0 >> 1) : 0)) * Hdim + seg;
    const ushort_t* srcA1 = hsb + (long)((s1 >= 0 ? (s1 >> 1) : 0)) * Hdim + seg;
    const ushort_t* srcB0 = w1b + ((long)e * 2 * Fdim + (f0 + rA0)) * Hdim + seg;          // gate
    const ushort_t* srcB1 = w1b + ((long)e * 2 * Fdim + Fdim + (f0 + rA0)) * Hdim + seg;   // up

    const int lane = tid & 63;
    const int w = tid >> 6;
    const int wm = (w >> 1) * 64;
    const int wn = (w & 1) * 32;
    const int fr = lane & 15, fg = lane >> 4;

    floatx4 accg[4][2] = {};
    floatx4 accu[4][2] = {};

    for (int k0 = 0; k0 < Hdim; k0 += 32) {
        __syncthreads();
        gld16(srcA0 + k0, &As[tid * 8]);
        gld16(srcA1 + k0, &As[(256 + tid) * 8]);
        gld16(srcB0 + k0, &Bs[tid * 8]);
        gld16(srcB1 + k0, &Bs[(256 + tid) * 8]);
        __syncthreads();

        bf16x8 a[4], g[2], u[2];
#pragma unroll
        for (int ms = 0; ms < 4; ++ms)
            a[ms] = *(bf16x8*)&As[(wm + ms * 16 + fr) * 32 + fg * 8];
#pragma unroll
        for (int ns = 0; ns < 2; ++ns) {
            g[ns] = *(bf16x8*)&Bs[(wn + ns * 16 + fr) * 32 + fg * 8];
            u[ns] = *(bf16x8*)&Bs[(64 + wn + ns * 16 + fr) * 32 + fg * 8];
        }
#pragma unroll
        for (int ms = 0; ms < 4; ++ms)
#pragma unroll
            for (int ns = 0; ns < 2; ++ns) {
                accg[ms][ns] = __builtin_amdgcn_mfma_f32_16x16x32_bf16(a[ms], g[ns], accg[ms][ns], 0, 0, 0);
                accu[ms][ns] = __builtin_amdgcn_mfma_f32_16x16x32_bf16(a[ms], u[ns], accu[ms][ns], 0, 0, 0);
            }
    }

#pragma unroll
    for (int ms = 0; ms < 4; ++ms)
#pragma unroll
        for (int ns = 0; ns < 2; ++ns)
#pragma unroll
            for (int j = 0; j < 4; ++j) {
                int m = wm + ms * 16 + fg * 4 + j;
                int slot = slotLds[m];
                if (slot >= 0) {
                    int fcol = f0 + wn + ns * 16 + fr;
                    float gv = accg[ms][ns][j];
                    float uv = accu[ms][ns][j];
                    float av = (gv / (1.f + __expf(-gv))) * uv;
                    actb[(long)slot * Fdim + fcol] = f2bf(av);
                }
            }
}

// ---------------------------------------------------------------------------
// K3: gather-GEMM2, 128x128, K=F. partial[slot, h] = wt * (act @ w2^T). Plain stores.
__global__ __launch_bounds__(256) void gemm2_kernel(
    const ushort_t* __restrict__ actb, const ushort_t* __restrict__ w2b,
    const int* __restrict__ counts, const int* __restrict__ tok_slot,
    const float* __restrict__ tok_wt, float* __restrict__ partial)
{
    const int e = blockIdx.z;
    const int cnt = counts[e];
    const int row0 = blockIdx.y * 128;
    if (row0 >= cnt) return;
    const int h0 = blockIdx.x * 128;

    __shared__ short As[128 * 32];
    __shared__ short Bs[128 * 32];
    __shared__ int   slotLds[128];
    __shared__ float wtLds[128];

    const int tid = threadIdx.x;
    if (tid < 128) {
        int idx = row0 + tid;
        bool ok = idx < cnt;
        slotLds[tid] = ok ? tok_slot[e * T + idx] : -1;
        wtLds[tid]   = ok ? tok_wt [e * T + idx] : 0.f;
    }
    __syncthreads();

    const int rA0 = tid >> 2, rA1 = 64 + (tid >> 2);
    const int seg = (tid & 3) * 8;
    int s0 = slotLds[rA0], s1 = slotLds[rA1];
    const ushort_t* srcA0 = actb + (long)(s0 >= 0 ? s0 : 0) * Fdim + seg;
    const ushort_t* srcA1 = actb + (long)(s1 >= 0 ? s1 : 0) * Fdim + seg;
    const ushort_t* srcB0 = w2b + ((long)e * Hdim + (h0 + rA0)) * Fdim + seg;
    const ushort_t* srcB1 = w2b + ((long)e * Hdim + (h0 + rA1)) * Fdim + seg;

    const int lane = tid & 63;
    const int w = tid >> 6;
    const int wm = (w >> 1) * 64;
    const int wn = (w & 1) * 64;
    const int fr = lane & 15, fg = lane >> 4;

    floatx4 acc[4][4] = {};

    for (int k0 = 0; k0 < Fdim; k0 += 32) {
        __syncthreads();
        gld16(srcA0 + k0, &As[tid * 8]);
        gld16(srcA1 + k0, &As[(256 + tid) * 8]);
        gld16(srcB0 + k0, &Bs[tid * 8]);
        gld16(srcB1 + k0, &Bs[(256 + tid) * 8]);
        __syncthreads();

        bf16x8 a[4], b[4];
#pragma unroll
        for (int ms = 0; ms < 4; ++ms)
            a[ms] = *(bf16x8*)&As[(wm + ms * 16 + fr) * 32 + fg * 8];
#pragma unroll
        for (int ns = 0; ns < 4; ++ns)
            b[ns] = *(bf16x8*)&Bs[(wn + ns * 16 + fr) * 32 + fg * 8];
#pragma unroll
        for (int ms = 0; ms < 4; ++ms)
#pragma unroll
            for (int ns = 0; ns < 4; ++ns)
                acc[ms][ns] = __builtin_amdgcn_mfma_f32_16x16x32_bf16(a[ms], b[ns], acc[ms][ns], 0, 0, 0);
    }

#pragma unroll
    for (int ms = 0; ms < 4; ++ms)
#pragma unroll
        for (int ns = 0; ns < 4; ++ns)
#pragma unroll
            for (int j = 0; j < 4; ++j) {
                int m = wm + ms * 16 + fg * 4 + j;
                int slot = slotLds[m];
                if (slot >= 0) {
                    int hcol = h0 + wn + ns * 16 + fr;
                    partial[(long)slot * Hdim + hcol] = acc[ms][ns][j] * wtLds[m];
                }
            }
}

// ---------------------------------------------------------------------------
// K4: combine the two (token,k) partials -> fp32 final hidden states
__global__ __launch_bounds__(256) void combine_kernel(
    const float* __restrict__ partial, float* __restrict__ out)
{
    long i = (long)blockIdx.x * 256 + threadIdx.x;   // over T*H/4 float4 groups
    int t  = (int)(i / (Hdim / 4));
    int h4 = (int)(i % (Hdim / 4));
    const float4 p0 = *(const float4*)&partial[(long)(2 * t    ) * Hdim + h4 * 4];
    const float4 p1 = *(const float4*)&partial[(long)(2 * t + 1) * Hdim + h4 * 4];
    float4 s;
    s.x = p0.x + p1.x; s.y = p0.y + p1.y; s.z = p0.z + p1.z; s.w = p0.w + p1.w;
    *(float4*)&out[(long)t * Hdim + h4 * 4] = s;
}

// ---------------------------------------------------------------------------
extern "C" void kernel_launch(void* const* d_in, const int* in_sizes, int n_in,
                              void* d_out, int out_size, void* d_ws, size_t ws_size,
                              hipStream_t stream)
{
    const float* hs = (const float*)d_in[0];   // [T, H] fp32
    const float* gw = (const float*)d_in[1];   // [E, H] fp32
    const float* w1 = (const float*)d_in[2];   // [E, 2F, H] fp32
    const float* w2 = (const float*)d_in[3];   // [E, H, F] fp32

    float* out        = (float*)d_out;          // [T*H] final hidden (fp32)
    float* logits_out = out + (long)T * Hdim;   // [T*E] router logits (fp32)

    // workspace layout (~104.3 MB, same footprint as round 3):
    // after gemm1, the 64 MB w1b region is recycled: lower 32 MB = w2b,
    // upper 32 MB = fp32 partial (stream-ordered reuse, no alias within a kernel)
    char* ws = (char*)d_ws;
    size_t off = 0;
    int* counts = (int*)(ws + off);          off += 256;
    int* tok_slot = (int*)(ws + off);        off += (size_t)NE * T * sizeof(int);
    float* tok_wt = (float*)(ws + off);      off += (size_t)NE * T * sizeof(float);
    off = (off + 255) & ~(size_t)255;
    ushort_t* hsb = (ushort_t*)(ws + off);   off += (size_t)T * Hdim * sizeof(ushort_t);   // 8 MB
    off = (off + 255) & ~(size_t)255;
    char* w1region = ws + off;               off += (size_t)NE * 2 * Fdim * Hdim * sizeof(ushort_t); // 64 MB
    ushort_t* w1b = (ushort_t*)w1region;
    ushort_t* w2b = (ushort_t*)w1region;                                     // 32 MB (lower half)
    float* partial = (float*)(w1region + (size_t)NE * Hdim * Fdim * sizeof(ushort_t)); // 32 MB (upper half)
    off = (off + 255) & ~(size_t)255;
    ushort_t* actb = (ushort_t*)(ws + off);  off += (size_t)TK * Fdim * sizeof(ushort_t);  // 32 MB

    init_kernel<<<1, 64, 0, stream>>>(counts);
    cvt_kernel<<<1024, 256, 0, stream>>>(hs, hsb, (long)T * Hdim / 8);
    cvt_kernel<<<2048, 256, 0, stream>>>(w1, w1b, (long)NE * 2 * Fdim * Hdim / 8);
    router_kernel<<<T, 64, 0, stream>>>(hs, gw, logits_out, counts, tok_slot, tok_wt);
    gemm1_kernel<<<dim3(Fdim / 64, T / 128, NE), 256, 0, stream>>>(hsb, w1b, counts, tok_slot, actb);
    cvt_kernel<<<2048, 256, 0, stream>>>(w2, w2b, (long)NE * Hdim * Fdim / 8);   // into recycled w1b (lower half)
    gemm2_kernel<<<dim3(Hdim / 128, T / 128, NE), 256, 0, stream>>>(actb, w2b, counts, tok_slot, tok_wt, partial);
    combine_kernel<<<(int)((long)T * Hdim / 4 / 256), 256, 0, stream>>>(partial, out);
}

// Round 5
// 440.928 us; speedup vs baseline: 1.4394x; 1.1972x over previous
//
#include <hip/hip_runtime.h>

// TBStars2 MoE sparse block — fp32 I/O, bf16 MFMA compute (m97-style GEMMs)
#define T 4096
#define Hdim 1024
#define Fdim 2048
#define NE 8
#define TOPK 2
#define TK (T*TOPK)

typedef unsigned short ushort_t;
typedef __attribute__((ext_vector_type(8))) short bf16x8;   // 8 x bf16 (4 VGPRs)
typedef __attribute__((ext_vector_type(4))) float floatx4;  // mfma accumulator

__device__ __forceinline__ ushort_t f2bf(float f) {
    unsigned u = __float_as_uint(f);
    u += 0x7fff + ((u >> 16) & 1);   // RNE
    return (ushort_t)(u >> 16);
}
__device__ __forceinline__ uint4 cvt8(const float4 a, const float4 b) {
    uint4 r;
    r.x = (unsigned)f2bf(a.x) | ((unsigned)f2bf(a.y) << 16);
    r.y = (unsigned)f2bf(a.z) | ((unsigned)f2bf(a.w) << 16);
    r.z = (unsigned)f2bf(b.x) | ((unsigned)f2bf(b.y) << 16);
    r.w = (unsigned)f2bf(b.z) | ((unsigned)f2bf(b.w) << 16);
    return r;
}
// async 16B global->LDS (per-lane gather src; LDS dest = wave base + lane*16)
__device__ __forceinline__ void gld16(const ushort_t* g, short* l) {
    __builtin_amdgcn_global_load_lds((const __attribute__((address_space(1))) void*)g,
                                     (__attribute__((address_space(3))) void*)l, 16, 0, 0);
}

// ---------------------------------------------------------------------------
// K0: zero per-expert counts
__global__ void init_kernel(int* __restrict__ counts) {
    if (threadIdx.x < NE) counts[threadIdx.x] = 0;
}

// K0b: fp32 -> bf16 bulk convert (grid-stride, 8 elems/thread/iter)
__global__ __launch_bounds__(256) void cvt_kernel(const float* __restrict__ src,
                                                  ushort_t* __restrict__ dst, long n8) {
    long stride = (long)gridDim.x * 256;
    for (long i = (long)blockIdx.x * 256 + threadIdx.x; i < n8; i += stride) {
        float4 a = *(const float4*)(src + i * 8);
        float4 b = *(const float4*)(src + i * 8 + 4);
        *(uint4*)(dst + i * 8) = cvt8(a, b);
    }
}

// ---------------------------------------------------------------------------
// K1: router. One wave per token, fp32. NO atomics — writes per-token choice.
__global__ __launch_bounds__(64) void router_kernel(
    const float* __restrict__ hs, const float* __restrict__ gw,
    float* __restrict__ logits_out,
    int2* __restrict__ choice, float2* __restrict__ cwt)
{
    const int t = blockIdx.x;
    const int lane = threadIdx.x;

    float hreg[16];
#pragma unroll
    for (int i = 0; i < 16; ++i)
        hreg[i] = hs[(long)t * Hdim + lane + 64 * i];

    float acc[NE];
#pragma unroll
    for (int e = 0; e < NE; ++e) {
        float s = 0.f;
#pragma unroll
        for (int i = 0; i < 16; ++i)
            s += hreg[i] * gw[e * Hdim + lane + 64 * i];
#pragma unroll
        for (int off = 32; off > 0; off >>= 1)
            s += __shfl_xor(s, off, 64);
        acc[e] = s;
    }

    if (lane < NE) logits_out[t * NE + lane] = acc[lane];

    if (lane == 0) {
        int i1 = 0;
#pragma unroll
        for (int e = 1; e < NE; ++e) if (acc[e] > acc[i1]) i1 = e;
        int i2 = -1;
#pragma unroll
        for (int e = 0; e < NE; ++e) {
            if (e == i1) continue;
            if (i2 < 0 || acc[e] > acc[i2]) i2 = e;
        }
        float p2 = __expf(acc[i2] - acc[i1]);
        float z  = 1.f + p2;
        choice[t] = make_int2(i1, i2);
        cwt[t]    = make_float2(1.f / z, p2 / z);
    }
}

// K1b: scatter. Block = 256 tokens. LDS histogram -> 8 global atomics/block
// (128 total, vs 8192 same-line atomics before) -> conflict-free list writes.
__global__ __launch_bounds__(256) void scatter_kernel(
    const int2* __restrict__ choice, const float2* __restrict__ cwt,
    int* __restrict__ counts, int* __restrict__ tok_slot, float* __restrict__ tok_wt)
{
    __shared__ int lhist[NE];
    __shared__ int lbase[NE];
    __shared__ int lpos[NE];
    const int tid = threadIdx.x;
    if (tid < NE) { lhist[tid] = 0; lpos[tid] = 0; }
    __syncthreads();

    const int t = blockIdx.x * 256 + tid;
    int2   ch = choice[t];
    float2 wv = cwt[t];
    atomicAdd(&lhist[ch.x], 1);
    atomicAdd(&lhist[ch.y], 1);
    __syncthreads();

    if (tid < NE) lbase[tid] = atomicAdd(&counts[tid], lhist[tid]);
    __syncthreads();

    int p1 = atomicAdd(&lpos[ch.x], 1);   // ch.x != ch.y (top-2 distinct)
    int p2 = atomicAdd(&lpos[ch.y], 1);
    int o1 = lbase[ch.x] + p1;
    int o2 = lbase[ch.y] + p2;
    tok_slot[ch.x * T + o1] = t * TOPK + 0;
    tok_wt [ch.x * T + o1] = wv.x;
    tok_slot[ch.y * T + o2] = t * TOPK + 1;
    tok_wt [ch.y * T + o2] = wv.y;
}

// ---------------------------------------------------------------------------
// K2: gather-GEMM1 + SwiGLU. Tile: 128 rows x 64 f-cols (gate+up both staged).
__global__ __launch_bounds__(256) void gemm1_kernel(
    const ushort_t* __restrict__ hsb, const ushort_t* __restrict__ w1b,
    const int* __restrict__ counts, const int* __restrict__ tok_slot,
    ushort_t* __restrict__ actb)
{
    const int e = blockIdx.z;
    const int cnt = counts[e];
    const int row0 = blockIdx.y * 128;
    if (row0 >= cnt) return;
    const int f0 = blockIdx.x * 64;

    __shared__ short As[128 * 32];    // 8 KB, row stride 32 elems (64 B)
    __shared__ short Bs[128 * 32];    // rows 0-63 gate, 64-127 up
    __shared__ int slotLds[128];

    const int tid = threadIdx.x;
    if (tid < 128) {
        int idx = row0 + tid;
        slotLds[tid] = (idx < cnt) ? tok_slot[e * T + idx] : -1;
    }
    __syncthreads();

    const int rA0 = tid >> 2,      rA1 = 64 + (tid >> 2);
    const int seg = (tid & 3) * 8;
    int s0 = slotLds[rA0], s1 = slotLds[rA1];
    const ushort_t* srcA0 = hsb + (long)((s0 >= 0 ? (s0 >> 1) : 0)) * Hdim + seg;
    const ushort_t* srcA1 = hsb + (long)((s1 >= 0 ? (s1 >> 1) : 0)) * Hdim + seg;
    const ushort_t* srcB0 = w1b + ((long)e * 2 * Fdim + (f0 + rA0)) * Hdim + seg;          // gate
    const ushort_t* srcB1 = w1b + ((long)e * 2 * Fdim + Fdim + (f0 + rA0)) * Hdim + seg;   // up

    const int lane = tid & 63;
    const int w = tid >> 6;
    const int wm = (w >> 1) * 64;
    const int wn = (w & 1) * 32;
    const int fr = lane & 15, fg = lane >> 4;

    floatx4 accg[4][2] = {};
    floatx4 accu[4][2] = {};

    for (int k0 = 0; k0 < Hdim; k0 += 32) {
        __syncthreads();
        gld16(srcA0 + k0, &As[tid * 8]);
        gld16(srcA1 + k0, &As[(256 + tid) * 8]);
        gld16(srcB0 + k0, &Bs[tid * 8]);
        gld16(srcB1 + k0, &Bs[(256 + tid) * 8]);
        __syncthreads();

        bf16x8 a[4], g[2], u[2];
#pragma unroll
        for (int ms = 0; ms < 4; ++ms)
            a[ms] = *(bf16x8*)&As[(wm + ms * 16 + fr) * 32 + fg * 8];
#pragma unroll
        for (int ns = 0; ns < 2; ++ns) {
            g[ns] = *(bf16x8*)&Bs[(wn + ns * 16 + fr) * 32 + fg * 8];
            u[ns] = *(bf16x8*)&Bs[(64 + wn + ns * 16 + fr) * 32 + fg * 8];
        }
#pragma unroll
        for (int ms = 0; ms < 4; ++ms)
#pragma unroll
            for (int ns = 0; ns < 2; ++ns) {
                accg[ms][ns] = __builtin_amdgcn_mfma_f32_16x16x32_bf16(a[ms], g[ns], accg[ms][ns], 0, 0, 0);
                accu[ms][ns] = __builtin_amdgcn_mfma_f32_16x16x32_bf16(a[ms], u[ns], accu[ms][ns], 0, 0, 0);
            }
    }

#pragma unroll
    for (int ms = 0; ms < 4; ++ms)
#pragma unroll
        for (int ns = 0; ns < 2; ++ns)
#pragma unroll
            for (int j = 0; j < 4; ++j) {
                int m = wm + ms * 16 + fg * 4 + j;
                int slot = slotLds[m];
                if (slot >= 0) {
                    int fcol = f0 + wn + ns * 16 + fr;
                    float gv = accg[ms][ns][j];
                    float uv = accu[ms][ns][j];
                    float av = (gv / (1.f + __expf(-gv))) * uv;
                    actb[(long)slot * Fdim + fcol] = f2bf(av);
                }
            }
}

// ---------------------------------------------------------------------------
// K3: gather-GEMM2, 128x128, K=F. partial[slot, h] = wt * (act @ w2^T). Plain stores.
__global__ __launch_bounds__(256) void gemm2_kernel(
    const ushort_t* __restrict__ actb, const ushort_t* __restrict__ w2b,
    const int* __restrict__ counts, const int* __restrict__ tok_slot,
    const float* __restrict__ tok_wt, float* __restrict__ partial)
{
    const int e = blockIdx.z;
    const int cnt = counts[e];
    const int row0 = blockIdx.y * 128;
    if (row0 >= cnt) return;
    const int h0 = blockIdx.x * 128;

    __shared__ short As[128 * 32];
    __shared__ short Bs[128 * 32];
    __shared__ int   slotLds[128];
    __shared__ float wtLds[128];

    const int tid = threadIdx.x;
    if (tid < 128) {
        int idx = row0 + tid;
        bool ok = idx < cnt;
        slotLds[tid] = ok ? tok_slot[e * T + idx] : -1;
        wtLds[tid]   = ok ? tok_wt [e * T + idx] : 0.f;
    }
    __syncthreads();

    const int rA0 = tid >> 2, rA1 = 64 + (tid >> 2);
    const int seg = (tid & 3) * 8;
    int s0 = slotLds[rA0], s1 = slotLds[rA1];
    const ushort_t* srcA0 = actb + (long)(s0 >= 0 ? s0 : 0) * Fdim + seg;
    const ushort_t* srcA1 = actb + (long)(s1 >= 0 ? s1 : 0) * Fdim + seg;
    const ushort_t* srcB0 = w2b + ((long)e * Hdim + (h0 + rA0)) * Fdim + seg;
    const ushort_t* srcB1 = w2b + ((long)e * Hdim + (h0 + rA1)) * Fdim + seg;

    const int lane = tid & 63;
    const int w = tid >> 6;
    const int wm = (w >> 1) * 64;
    const int wn = (w & 1) * 64;
    const int fr = lane & 15, fg = lane >> 4;

    floatx4 acc[4][4] = {};

    for (int k0 = 0; k0 < Fdim; k0 += 32) {
        __syncthreads();
        gld16(srcA0 + k0, &As[tid * 8]);
        gld16(srcA1 + k0, &As[(256 + tid) * 8]);
        gld16(srcB0 + k0, &Bs[tid * 8]);
        gld16(srcB1 + k0, &Bs[(256 + tid) * 8]);
        __syncthreads();

        bf16x8 a[4], b[4];
#pragma unroll
        for (int ms = 0; ms < 4; ++ms)
            a[ms] = *(bf16x8*)&As[(wm + ms * 16 + fr) * 32 + fg * 8];
#pragma unroll
        for (int ns = 0; ns < 4; ++ns)
            b[ns] = *(bf16x8*)&Bs[(wn + ns * 16 + fr) * 32 + fg * 8];
#pragma unroll
        for (int ms = 0; ms < 4; ++ms)
#pragma unroll
            for (int ns = 0; ns < 4; ++ns)
                acc[ms][ns] = __builtin_amdgcn_mfma_f32_16x16x32_bf16(a[ms], b[ns], acc[ms][ns], 0, 0, 0);
    }

#pragma unroll
    for (int ms = 0; ms < 4; ++ms)
#pragma unroll
        for (int ns = 0; ns < 4; ++ns)
#pragma unroll
            for (int j = 0; j < 4; ++j) {
                int m = wm + ms * 16 + fg * 4 + j;
                int slot = slotLds[m];
                if (slot >= 0) {
                    int hcol = h0 + wn + ns * 16 + fr;
                    partial[(long)slot * Hdim + hcol] = acc[ms][ns][j] * wtLds[m];
                }
            }
}

// ---------------------------------------------------------------------------
// K4: combine the two (token,k) partials -> fp32 final hidden states
__global__ __launch_bounds__(256) void combine_kernel(
    const float* __restrict__ partial, float* __restrict__ out)
{
    long i = (long)blockIdx.x * 256 + threadIdx.x;   // over T*H/4 float4 groups
    int t  = (int)(i / (Hdim / 4));
    int h4 = (int)(i % (Hdim / 4));
    const float4 p0 = *(const float4*)&partial[(long)(2 * t    ) * Hdim + h4 * 4];
    const float4 p1 = *(const float4*)&partial[(long)(2 * t + 1) * Hdim + h4 * 4];
    float4 s;
    s.x = p0.x + p1.x; s.y = p0.y + p1.y; s.z = p0.z + p1.z; s.w = p0.w + p1.w;
    *(float4*)&out[(long)t * Hdim + h4 * 4] = s;
}

// ---------------------------------------------------------------------------
extern "C" void kernel_launch(void* const* d_in, const int* in_sizes, int n_in,
                              void* d_out, int out_size, void* d_ws, size_t ws_size,
                              hipStream_t stream)
{
    const float* hs = (const float*)d_in[0];   // [T, H] fp32
    const float* gw = (const float*)d_in[1];   // [E, H] fp32
    const float* w1 = (const float*)d_in[2];   // [E, 2F, H] fp32
    const float* w2 = (const float*)d_in[3];   // [E, H, F] fp32

    float* out        = (float*)d_out;          // [T*H] final hidden (fp32)
    float* logits_out = out + (long)T * Hdim;   // [T*E] router logits (fp32)

    // workspace layout (~104.3 MB, unchanged footprint):
    // w1region recycled after gemm1: lower 32 MB = w2b, upper 32 MB = partial.
    // choice/cwt alias the first 64 KB of actb (consumed before gemm1 writes it).
    char* ws = (char*)d_ws;
    size_t off = 0;
    int* counts = (int*)(ws + off);          off += 256;
    int* tok_slot = (int*)(ws + off);        off += (size_t)NE * T * sizeof(int);
    float* tok_wt = (float*)(ws + off);      off += (size_t)NE * T * sizeof(float);
    off = (off + 255) & ~(size_t)255;
    ushort_t* hsb = (ushort_t*)(ws + off);   off += (size_t)T * Hdim * sizeof(ushort_t);   // 8 MB
    off = (off + 255) & ~(size_t)255;
    char* w1region = ws + off;               off += (size_t)NE * 2 * Fdim * Hdim * sizeof(ushort_t); // 64 MB
    ushort_t* w1b = (ushort_t*)w1region;
    ushort_t* w2b = (ushort_t*)w1region;                                     // 32 MB (lower half)
    float* partial = (float*)(w1region + (size_t)NE * Hdim * Fdim * sizeof(ushort_t)); // 32 MB (upper half)
    off = (off + 255) & ~(size_t)255;
    ushort_t* actb = (ushort_t*)(ws + off);  off += (size_t)TK * Fdim * sizeof(ushort_t);  // 32 MB
    int2*   choice = (int2*)actb;                       // 32 KB  (dead before gemm1)
    float2* cwt    = (float2*)((char*)actb + (size_t)T * sizeof(int2));   // 32 KB

    init_kernel<<<1, 64, 0, stream>>>(counts);
    cvt_kernel<<<1024, 256, 0, stream>>>(hs, hsb, (long)T * Hdim / 8);
    cvt_kernel<<<2048, 256, 0, stream>>>(w1, w1b, (long)NE * 2 * Fdim * Hdim / 8);
    router_kernel<<<T, 64, 0, stream>>>(hs, gw, logits_out, choice, cwt);
    scatter_kernel<<<T / 256, 256, 0, stream>>>(choice, cwt, counts, tok_slot, tok_wt);
    gemm1_kernel<<<dim3(Fdim / 64, T / 128, NE), 256, 0, stream>>>(hsb, w1b, counts, tok_slot, actb);
    cvt_kernel<<<2048, 256, 0, stream>>>(w2, w2b, (long)NE * Hdim * Fdim / 8);   // into recycled w1b (lower half)
    gemm2_kernel<<<dim3(Hdim / 128, T / 128, NE), 256, 0, stream>>>(actb, w2b, counts, tok_slot, tok_wt, partial);
    combine_kernel<<<(int)((long)T * Hdim / 4 / 256), 256, 0, stream>>>(partial, out);
}

// Round 6
// 437.257 us; speedup vs baseline: 1.4515x; 1.0084x over previous
//
#include <hip/hip_runtime.h>

// TBStars2 MoE sparse block — fp32 I/O, bf16 MFMA compute (m97-style GEMMs)
#define T 4096
#define Hdim 1024
#define Fdim 2048
#define NE 8
#define TOPK 2
#define TK (T*TOPK)

typedef unsigned short ushort_t;
typedef __attribute__((ext_vector_type(8))) short bf16x8;   // 8 x bf16 (4 VGPRs)
typedef __attribute__((ext_vector_type(4))) float floatx4;  // mfma accumulator

__device__ __forceinline__ ushort_t f2bf(float f) {
    unsigned u = __float_as_uint(f);
    u += 0x7fff + ((u >> 16) & 1);   // RNE
    return (ushort_t)(u >> 16);
}
__device__ __forceinline__ uint4 cvt8(const float4 a, const float4 b) {
    uint4 r;
    r.x = (unsigned)f2bf(a.x) | ((unsigned)f2bf(a.y) << 16);
    r.y = (unsigned)f2bf(a.z) | ((unsigned)f2bf(a.w) << 16);
    r.z = (unsigned)f2bf(b.x) | ((unsigned)f2bf(b.y) << 16);
    r.w = (unsigned)f2bf(b.z) | ((unsigned)f2bf(b.w) << 16);
    return r;
}
// async 16B global->LDS (per-lane gather src; LDS dest = wave base + lane*16)
__device__ __forceinline__ void gld16(const ushort_t* g, short* l) {
    __builtin_amdgcn_global_load_lds((const __attribute__((address_space(1))) void*)g,
                                     (__attribute__((address_space(3))) void*)l, 16, 0, 0);
}

// ---------------------------------------------------------------------------
// K0: merged fp32->bf16 convert for hs (n8A groups) then w1 (rest). Exact grid,
// one 8-elem group per thread — no loop. 216 MB traffic: if this kernel is
// slow it will surface in the top-5 profile.
__global__ __launch_bounds__(256) void cvt2_kernel(
    const float* __restrict__ srcA, ushort_t* __restrict__ dstA, long n8A,
    const float* __restrict__ srcB, ushort_t* __restrict__ dstB)
{
    long i = (long)blockIdx.x * 256 + threadIdx.x;
    if (i < n8A) {
        float4 a = *(const float4*)(srcA + i * 8);
        float4 b = *(const float4*)(srcA + i * 8 + 4);
        *(uint4*)(dstA + i * 8) = cvt8(a, b);
    } else {
        long j = i - n8A;
        float4 a = *(const float4*)(srcB + j * 8);
        float4 b = *(const float4*)(srcB + j * 8 + 4);
        *(uint4*)(dstB + j * 8) = cvt8(a, b);
    }
}

// K0b: fp32 -> bf16 convert, exact grid (for w2)
__global__ __launch_bounds__(256) void cvt_kernel(const float* __restrict__ src,
                                                  ushort_t* __restrict__ dst)
{
    long i = (long)blockIdx.x * 256 + threadIdx.x;
    float4 a = *(const float4*)(src + i * 8);
    float4 b = *(const float4*)(src + i * 8 + 4);
    *(uint4*)(dst + i * 8) = cvt8(a, b);
}

// ---------------------------------------------------------------------------
// K1: router. One wave per token, fp32. No atomics. Block 0 zeroes counts
// (safe: counts consumed only by the NEXT kernel).
__global__ __launch_bounds__(64) void router_kernel(
    const float* __restrict__ hs, const float* __restrict__ gw,
    float* __restrict__ logits_out,
    int2* __restrict__ choice, float2* __restrict__ cwt, int* __restrict__ counts)
{
    const int t = blockIdx.x;
    const int lane = threadIdx.x;
    if (t == 0 && lane < NE) counts[lane] = 0;

    float hreg[16];
#pragma unroll
    for (int i = 0; i < 16; ++i)
        hreg[i] = hs[(long)t * Hdim + lane + 64 * i];

    float acc[NE];
#pragma unroll
    for (int e = 0; e < NE; ++e) {
        float s = 0.f;
#pragma unroll
        for (int i = 0; i < 16; ++i)
            s += hreg[i] * gw[e * Hdim + lane + 64 * i];
#pragma unroll
        for (int off = 32; off > 0; off >>= 1)
            s += __shfl_xor(s, off, 64);
        acc[e] = s;
    }

    if (lane < NE) logits_out[t * NE + lane] = acc[lane];

    if (lane == 0) {
        int i1 = 0;
#pragma unroll
        for (int e = 1; e < NE; ++e) if (acc[e] > acc[i1]) i1 = e;
        int i2 = -1;
#pragma unroll
        for (int e = 0; e < NE; ++e) {
            if (e == i1) continue;
            if (i2 < 0 || acc[e] > acc[i2]) i2 = e;
        }
        float p2 = __expf(acc[i2] - acc[i1]);
        float z  = 1.f + p2;
        choice[t] = make_int2(i1, i2);
        cwt[t]    = make_float2(1.f / z, p2 / z);
    }
}

// K1b: scatter. Block = 256 tokens. LDS histogram -> 8 global atomics/block.
__global__ __launch_bounds__(256) void scatter_kernel(
    const int2* __restrict__ choice, const float2* __restrict__ cwt,
    int* __restrict__ counts, int* __restrict__ tok_slot, float* __restrict__ tok_wt)
{
    __shared__ int lhist[NE];
    __shared__ int lbase[NE];
    __shared__ int lpos[NE];
    const int tid = threadIdx.x;
    if (tid < NE) { lhist[tid] = 0; lpos[tid] = 0; }
    __syncthreads();

    const int t = blockIdx.x * 256 + tid;
    int2   ch = choice[t];
    float2 wv = cwt[t];
    atomicAdd(&lhist[ch.x], 1);
    atomicAdd(&lhist[ch.y], 1);
    __syncthreads();

    if (tid < NE) lbase[tid] = atomicAdd(&counts[tid], lhist[tid]);
    __syncthreads();

    int p1 = atomicAdd(&lpos[ch.x], 1);   // ch.x != ch.y (top-2 distinct)
    int p2 = atomicAdd(&lpos[ch.y], 1);
    int o1 = lbase[ch.x] + p1;
    int o2 = lbase[ch.y] + p2;
    tok_slot[ch.x * T + o1] = t * TOPK + 0;
    tok_wt [ch.x * T + o1] = wv.x;
    tok_slot[ch.y * T + o2] = t * TOPK + 1;
    tok_wt [ch.y * T + o2] = wv.y;
}

// ---------------------------------------------------------------------------
// K2: gather-GEMM1 + SwiGLU. Tile: 128 rows x 64 f-cols (gate+up both staged).
__global__ __launch_bounds__(256) void gemm1_kernel(
    const ushort_t* __restrict__ hsb, const ushort_t* __restrict__ w1b,
    const int* __restrict__ counts, const int* __restrict__ tok_slot,
    ushort_t* __restrict__ actb)
{
    const int e = blockIdx.z;
    const int cnt = counts[e];
    const int row0 = blockIdx.y * 128;
    if (row0 >= cnt) return;
    const int f0 = blockIdx.x * 64;

    __shared__ short As[128 * 32];    // 8 KB, row stride 32 elems (64 B)
    __shared__ short Bs[128 * 32];    // rows 0-63 gate, 64-127 up
    __shared__ int slotLds[128];

    const int tid = threadIdx.x;
    if (tid < 128) {
        int idx = row0 + tid;
        slotLds[tid] = (idx < cnt) ? tok_slot[e * T + idx] : -1;
    }
    __syncthreads();

    const int rA0 = tid >> 2,      rA1 = 64 + (tid >> 2);
    const int seg = (tid & 3) * 8;
    int s0 = slotLds[rA0], s1 = slotLds[rA1];
    const ushort_t* srcA0 = hsb + (long)((s0 >= 0 ? (s0 >> 1) : 0)) * Hdim + seg;
    const ushort_t* srcA1 = hsb + (long)((s1 >= 0 ? (s1 >> 1) : 0)) * Hdim + seg;
    const ushort_t* srcB0 = w1b + ((long)e * 2 * Fdim + (f0 + rA0)) * Hdim + seg;          // gate
    const ushort_t* srcB1 = w1b + ((long)e * 2 * Fdim + Fdim + (f0 + rA0)) * Hdim + seg;   // up

    const int lane = tid & 63;
    const int w = tid >> 6;
    const int wm = (w >> 1) * 64;
    const int wn = (w & 1) * 32;
    const int fr = lane & 15, fg = lane >> 4;

    floatx4 accg[4][2] = {};
    floatx4 accu[4][2] = {};

    for (int k0 = 0; k0 < Hdim; k0 += 32) {
        __syncthreads();
        gld16(srcA0 + k0, &As[tid * 8]);
        gld16(srcA1 + k0, &As[(256 + tid) * 8]);
        gld16(srcB0 + k0, &Bs[tid * 8]);
        gld16(srcB1 + k0, &Bs[(256 + tid) * 8]);
        __syncthreads();

        bf16x8 a[4], g[2], u[2];
#pragma unroll
        for (int ms = 0; ms < 4; ++ms)
            a[ms] = *(bf16x8*)&As[(wm + ms * 16 + fr) * 32 + fg * 8];
#pragma unroll
        for (int ns = 0; ns < 2; ++ns) {
            g[ns] = *(bf16x8*)&Bs[(wn + ns * 16 + fr) * 32 + fg * 8];
            u[ns] = *(bf16x8*)&Bs[(64 + wn + ns * 16 + fr) * 32 + fg * 8];
        }
#pragma unroll
        for (int ms = 0; ms < 4; ++ms)
#pragma unroll
            for (int ns = 0; ns < 2; ++ns) {
                accg[ms][ns] = __builtin_amdgcn_mfma_f32_16x16x32_bf16(a[ms], g[ns], accg[ms][ns], 0, 0, 0);
                accu[ms][ns] = __builtin_amdgcn_mfma_f32_16x16x32_bf16(a[ms], u[ns], accu[ms][ns], 0, 0, 0);
            }
    }

#pragma unroll
    for (int ms = 0; ms < 4; ++ms)
#pragma unroll
        for (int ns = 0; ns < 2; ++ns)
#pragma unroll
            for (int j = 0; j < 4; ++j) {
                int m = wm + ms * 16 + fg * 4 + j;
                int slot = slotLds[m];
                if (slot >= 0) {
                    int fcol = f0 + wn + ns * 16 + fr;
                    float gv = accg[ms][ns][j];
                    float uv = accu[ms][ns][j];
                    float av = (gv / (1.f + __expf(-gv))) * uv;
                    actb[(long)slot * Fdim + fcol] = f2bf(av);
                }
            }
}

// ---------------------------------------------------------------------------
// K3: gather-GEMM2, 128x128 tile, 512 threads (8 waves, 2x4 wave grid).
// Wave tile 64x32: 8 MFMA per K-step, 2 gld16 per thread. 16 waves/CU at the
// 512-active-block occupancy (was 8 with 256-thread blocks).
__global__ __launch_bounds__(512) void gemm2_kernel(
    const ushort_t* __restrict__ actb, const ushort_t* __restrict__ w2b,
    const int* __restrict__ counts, const int* __restrict__ tok_slot,
    const float* __restrict__ tok_wt, float* __restrict__ partial)
{
    const int e = blockIdx.z;
    const int cnt = counts[e];
    const int row0 = blockIdx.y * 128;
    if (row0 >= cnt) return;
    const int h0 = blockIdx.x * 128;

    __shared__ short As[128 * 32];
    __shared__ short Bs[128 * 32];
    __shared__ int   slotLds[128];
    __shared__ float wtLds[128];

    const int tid = threadIdx.x;
    if (tid < 128) {
        int idx = row0 + tid;
        bool ok = idx < cnt;
        slotLds[tid] = ok ? tok_slot[e * T + idx] : -1;
        wtLds[tid]   = ok ? tok_wt [e * T + idx] : 0.f;
    }
    __syncthreads();

    // staging: one 16B A-chunk + one 16B B-chunk per thread per K-step
    const int r   = tid >> 2;            // 0..127
    const int seg = (tid & 3) * 8;
    int s = slotLds[r];
    const ushort_t* srcA = actb + (long)(s >= 0 ? s : 0) * Fdim + seg;
    const ushort_t* srcB = w2b + ((long)e * Hdim + (h0 + r)) * Fdim + seg;

    const int lane = tid & 63;
    const int w = tid >> 6;              // 0..7
    const int wm = (w >> 2) * 64;        // 2 wave-rows
    const int wn = (w & 3) * 32;         // 4 wave-cols
    const int fr = lane & 15, fg = lane >> 4;

    floatx4 acc[4][2] = {};

    for (int k0 = 0; k0 < Fdim; k0 += 32) {
        __syncthreads();
        gld16(srcA + k0, &As[tid * 8]);
        gld16(srcB + k0, &Bs[tid * 8]);
        __syncthreads();

        bf16x8 a[4], b[2];
#pragma unroll
        for (int ms = 0; ms < 4; ++ms)
            a[ms] = *(bf16x8*)&As[(wm + ms * 16 + fr) * 32 + fg * 8];
#pragma unroll
        for (int ns = 0; ns < 2; ++ns)
            b[ns] = *(bf16x8*)&Bs[(wn + ns * 16 + fr) * 32 + fg * 8];
#pragma unroll
        for (int ms = 0; ms < 4; ++ms)
#pragma unroll
            for (int ns = 0; ns < 2; ++ns)
                acc[ms][ns] = __builtin_amdgcn_mfma_f32_16x16x32_bf16(a[ms], b[ns], acc[ms][ns], 0, 0, 0);
    }

#pragma unroll
    for (int ms = 0; ms < 4; ++ms)
#pragma unroll
        for (int ns = 0; ns < 2; ++ns)
#pragma unroll
            for (int j = 0; j < 4; ++j) {
                int m = wm + ms * 16 + fg * 4 + j;
                int slot = slotLds[m];
                if (slot >= 0) {
                    int hcol = h0 + wn + ns * 16 + fr;
                    partial[(long)slot * Hdim + hcol] = acc[ms][ns][j] * wtLds[m];
                }
            }
}

// ---------------------------------------------------------------------------
// K4: combine the two (token,k) partials -> fp32 final hidden states
__global__ __launch_bounds__(256) void combine_kernel(
    const float* __restrict__ partial, float* __restrict__ out)
{
    long i = (long)blockIdx.x * 256 + threadIdx.x;   // over T*H/4 float4 groups
    int t  = (int)(i / (Hdim / 4));
    int h4 = (int)(i % (Hdim / 4));
    const float4 p0 = *(const float4*)&partial[(long)(2 * t    ) * Hdim + h4 * 4];
    const float4 p1 = *(const float4*)&partial[(long)(2 * t + 1) * Hdim + h4 * 4];
    float4 s;
    s.x = p0.x + p1.x; s.y = p0.y + p1.y; s.z = p0.z + p1.z; s.w = p0.w + p1.w;
    *(float4*)&out[(long)t * Hdim + h4 * 4] = s;
}

// ---------------------------------------------------------------------------
extern "C" void kernel_launch(void* const* d_in, const int* in_sizes, int n_in,
                              void* d_out, int out_size, void* d_ws, size_t ws_size,
                              hipStream_t stream)
{
    const float* hs = (const float*)d_in[0];   // [T, H] fp32
    const float* gw = (const float*)d_in[1];   // [E, H] fp32
    const float* w1 = (const float*)d_in[2];   // [E, 2F, H] fp32
    const float* w2 = (const float*)d_in[3];   // [E, H, F] fp32

    float* out        = (float*)d_out;          // [T*H] final hidden (fp32)
    float* logits_out = out + (long)T * Hdim;   // [T*E] router logits (fp32)

    // workspace layout (~104.3 MB):
    // w1region recycled after gemm1: lower 32 MB = w2b, upper 32 MB = partial.
    // choice/cwt alias the first 64 KB of actb (dead before gemm1 writes it).
    char* ws = (char*)d_ws;
    size_t off = 0;
    int* counts = (int*)(ws + off);          off += 256;
    int* tok_slot = (int*)(ws + off);        off += (size_t)NE * T * sizeof(int);
    float* tok_wt = (float*)(ws + off);      off += (size_t)NE * T * sizeof(float);
    off = (off + 255) & ~(size_t)255;
    ushort_t* hsb = (ushort_t*)(ws + off);   off += (size_t)T * Hdim * sizeof(ushort_t);   // 8 MB
    off = (off + 255) & ~(size_t)255;
    char* w1region = ws + off;               off += (size_t)NE * 2 * Fdim * Hdim * sizeof(ushort_t); // 64 MB
    ushort_t* w1b = (ushort_t*)w1region;
    ushort_t* w2b = (ushort_t*)w1region;                                     // 32 MB (lower half)
    float* partial = (float*)(w1region + (size_t)NE * Hdim * Fdim * sizeof(ushort_t)); // 32 MB (upper half)
    off = (off + 255) & ~(size_t)255;
    ushort_t* actb = (ushort_t*)(ws + off);  off += (size_t)TK * Fdim * sizeof(ushort_t);  // 32 MB
    int2*   choice = (int2*)actb;                       // 32 KB  (dead before gemm1)
    float2* cwt    = (float2*)((char*)actb + (size_t)T * sizeof(int2));   // 32 KB

    const long n8_hs = (long)T * Hdim / 8;                    //   524288
    const long n8_w1 = (long)NE * 2 * Fdim * Hdim / 8;        //  4194304
    const long n8_w2 = (long)NE * Hdim * Fdim / 8;            //  2097152

    cvt2_kernel<<<(int)((n8_hs + n8_w1) / 256), 256, 0, stream>>>(hs, hsb, n8_hs, w1, w1b);
    router_kernel<<<T, 64, 0, stream>>>(hs, gw, logits_out, choice, cwt, counts);
    scatter_kernel<<<T / 256, 256, 0, stream>>>(choice, cwt, counts, tok_slot, tok_wt);
    gemm1_kernel<<<dim3(Fdim / 64, T / 128, NE), 256, 0, stream>>>(hsb, w1b, counts, tok_slot, actb);
    cvt_kernel<<<(int)(n8_w2 / 256), 256, 0, stream>>>(w2, w2b);   // into recycled w1b (lower half)
    gemm2_kernel<<<dim3(Hdim / 128, T / 128, NE), 512, 0, stream>>>(actb, w2b, counts, tok_slot, tok_wt, partial);
    combine_kernel<<<(int)((long)T * Hdim / 4 / 256), 256, 0, stream>>>(partial, out);
}